// Round 8
// baseline (99.466 us; speedup 1.0000x reference)
//
#include <hip/hip_runtime.h>
#include <hip/hip_bf16.h>

#define N_NODES  12288
#define N_FEAT   256
#define KDIM     128
#define N_GRAPHS 192
#define NMAX     112          // LDS fast-path max graph size (mean 64, std ~8)
#define KSTRIDE_U 68          // K LDS row stride in u32 (272 B; 4j mod 32 -> 2-way=free)
#define XS_STRIDE_U 132       // X LDS row stride in u32 (132%32=4 -> 2-way=free; 16B-aligned)

// workspace layout (bytes)
#define WS_STARTS 0
#define WS_U      1024                                  // fp32 U [192][256]
#define WS_WSLOW  (WS_U + N_GRAPHS * N_FEAT * 4)        // fp32 wslow [4][12288] (slow path)
#define WS_QB     (WS_WSLOW + 4 * N_NODES * 4)          // bf16 Q [12288][128] as u32[64]
#define WS_KB     (WS_QB + N_NODES * 64 * 4)            // bf16 K [12288][128] as u32[64]
#define WS_WT     (WS_KB + N_NODES * 64 * 4)            // bf16 Wt [256][256] as u32[128]

typedef __bf16 bf16x8 __attribute__((ext_vector_type(8)));
typedef float  f32x4  __attribute__((ext_vector_type(4)));

__device__ __forceinline__ unsigned bf16_rne(float f) {
  unsigned u = __float_as_uint(f);
  return (u + 0x7FFFu + ((u >> 16) & 1u)) >> 16;
}
__device__ __forceinline__ unsigned pack_bf16(float lo, float hi) {
  return bf16_rne(lo) | (bf16_rne(hi) << 16);
}
__device__ __forceinline__ float bf_lo(unsigned u) { return __uint_as_float(u << 16); }
__device__ __forceinline__ float bf_hi(unsigned u) { return __uint_as_float(u & 0xFFFF0000u); }

// ---------------------------------------------------------------------------
// Kernel 1: W pre-transpose to bf16 (Wt[n][k], packed u32 pairs) + segment
// starts (block n <= 192: starts[n] = lower_bound(batch, n); batch sorted).
// ---------------------------------------------------------------------------
__global__ __launch_bounds__(64) void wt_prep_k(const float* __restrict__ Wq,
                                                const float* __restrict__ Wk,
                                                const int* __restrict__ batch,
                                                unsigned* __restrict__ Wt,
                                                int* __restrict__ starts) {
  const int n = blockIdx.x;
  const int t = threadIdx.x;
  const float* src = (n < KDIM) ? (Wq + n) : (Wk + (n - KDIM));
  float f0 = src[(4 * t + 0) * KDIM];
  float f1 = src[(4 * t + 1) * KDIM];
  float f2 = src[(4 * t + 2) * KDIM];
  float f3 = src[(4 * t + 3) * KDIM];
  Wt[n * 128 + 2 * t]     = pack_bf16(f0, f1);
  Wt[n * 128 + 2 * t + 1] = pack_bf16(f2, f3);

  if (t == 0 && n <= N_GRAPHS) {
    int lo = 0, hi = N_NODES;
    while (lo < hi) {
      int mid = (lo + hi) >> 1;
      if (batch[mid] < n) lo = mid + 1; else hi = mid;
    }
    starts[n] = lo;
  }
}

// ---------------------------------------------------------------------------
// Kernel 2: fused Q|K projection via bf16 MFMA (unchanged from R7).
// ---------------------------------------------------------------------------
__global__ __launch_bounds__(256) void qk_proj_k(const float* __restrict__ X,
                                                 const unsigned* __restrict__ Wt,
                                                 unsigned* __restrict__ Qb,
                                                 unsigned* __restrict__ Kb) {
  __shared__ unsigned Xs_u[16 * XS_STRIDE_U];   // 8448 B

  const int tid  = threadIdx.x;
  const int lane = tid & 63;
  const int wv   = tid >> 6;
  const int r0   = blockIdx.x * 16;
  const int l15  = lane & 15;
  const int quad = lane >> 4;

  {
    const int row = tid >> 4, seg = tid & 15;
    const float* xp = &X[(size_t)(r0 + row) * N_FEAT + seg * 16];
    float4 a = *(const float4*)xp;
    float4 b = *(const float4*)(xp + 4);
    float4 c = *(const float4*)(xp + 8);
    float4 d = *(const float4*)(xp + 12);
    unsigned* dst = &Xs_u[row * XS_STRIDE_U + seg * 8];
    *(uint4*)dst       = make_uint4(pack_bf16(a.x, a.y), pack_bf16(a.z, a.w),
                                    pack_bf16(b.x, b.y), pack_bf16(b.z, b.w));
    *(uint4*)(dst + 4) = make_uint4(pack_bf16(c.x, c.y), pack_bf16(c.z, c.w),
                                    pack_bf16(d.x, d.y), pack_bf16(d.z, d.w));
  }
  __syncthreads();

  f32x4 acc[4];
#pragma unroll
  for (int ni = 0; ni < 4; ni++) acc[ni] = (f32x4){0.f, 0.f, 0.f, 0.f};

#pragma unroll
  for (int ks = 0; ks < 8; ks++) {
    bf16x8 a = *(const bf16x8*)&Xs_u[l15 * XS_STRIDE_U + ks * 16 + quad * 4];
    bf16x8 b[4];
#pragma unroll
    for (int ni = 0; ni < 4; ni++)
      b[ni] = *(const bf16x8*)&Wt[(size_t)(wv * 64 + ni * 16 + l15) * 128 + ks * 16 + quad * 4];
#pragma unroll
    for (int ni = 0; ni < 4; ni++)
      acc[ni] = __builtin_amdgcn_mfma_f32_16x16x32_bf16(a, b[ni], acc[ni], 0, 0, 0);
  }

  unsigned* dst = (wv < 2) ? Qb : Kb;
  const float scale = (wv < 2) ? 0.0625f : 1.0f;
  const int colbase = (wv & 1) * 64;
#pragma unroll
  for (int ni = 0; ni < 4; ni++) {
    const int col = colbase + ni * 16 + l15;
#pragma unroll
    for (int e = 0; e < 4; e++) {
      const int row = r0 + quad * 4 + e;
      unsigned b = bf16_rne(acc[ni][e] * scale);
      unsigned partner = __shfl_xor((int)b, 1);
      if ((lane & 1) == 0)
        dst[row * 64 + (col >> 1)] = b | (partner << 16);
    }
  }
}

// ---------------------------------------------------------------------------
// Kernel 3: per-(graph, f-quarter) — w (redundant per block, cheap MFMA) +
// u-quarter.  4 blocks/graph = 768 blocks x 512 thr.
// Phase A (identical in all 4 blocks): stage K tile -> wave s = strip s
//   (7 col-groups x 4 k-steps MFMA) -> in-wave softmax -> column weights ->
//   w in LDS.
// Phase B: u[f] = sum_j w[j] X[i0+j][f] for this block's 64 features only
//   (8-way j-split, LDS reduce), write U[g][f-quarter]. No atomics.
// Slow path (n > NMAX): private wslow segment per (g,qi) -> race-free.
// ---------------------------------------------------------------------------
__global__ __launch_bounds__(512) void attn_u_k(const float* __restrict__ X,
                                                const int* __restrict__ starts,
                                                const unsigned* __restrict__ Qb,
                                                const unsigned* __restrict__ Kb,
                                                float* __restrict__ U,
                                                float* __restrict__ wslow) {
  __shared__ unsigned Ks_u[NMAX * KSTRIDE_U];   // 30464 B
  __shared__ float    w_lds[8][NMAX];           // 3584 B
  __shared__ float    red[8][64];               // 2048 B

  const int tid  = threadIdx.x;
  const int lane = tid & 63;
  const int wv   = tid >> 6;
  const int l15  = lane & 15;
  const int quad = lane >> 4;
  const int g    = blockIdx.x >> 2;
  const int qi   = blockIdx.x & 3;

  const int i0 = starts[g];
  const int n  = starts[g + 1] - i0;
  const float BIG = 1e30f;
  const bool fast = (n <= NMAX);
  float* seg = wslow + (size_t)qi * N_NODES;    // slow-path private w segment

  if (fast) {
    // ---- stage K tile ----
    for (int idx = tid; idx < n * 16; idx += 512) {
      int j = idx >> 4, c = idx & 15;
      *(uint4*)&Ks_u[j * KSTRIDE_U + 4 * c] = *(const uint4*)&Kb[(size_t)(i0 + j) * 64 + 4 * c];
    }
    __syncthreads();

    float wl[7];
#pragma unroll
    for (int f = 0; f < 7; f++) wl[f] = 0.f;

    const int ns = (n + 15) >> 4;   // strips; wave s handles strip s
    if (wv < ns) {
      const int s = wv;
      const int arow = min(s * 16 + l15, n - 1);
      const unsigned* qrow = &Qb[(size_t)(i0 + arow) * 64];
      bf16x8 au[4];
#pragma unroll
      for (int ks = 0; ks < 4; ks++)
        au[ks] = *(const bf16x8*)&qrow[ks * 16 + quad * 4];

      f32x4 acc[7];
#pragma unroll
      for (int f = 0; f < 7; f++) acc[f] = (f32x4){0.f, 0.f, 0.f, 0.f};
#pragma unroll
      for (int f = 0; f < 7; f++) {
#pragma unroll
        for (int ks = 0; ks < 4; ks++) {
          bf16x8 bu = *(const bf16x8*)&Ks_u[(f * 16 + l15) * KSTRIDE_U + ks * 16 + quad * 4];
          acc[f] = __builtin_amdgcn_mfma_f32_16x16x32_bf16(au[ks], bu, acc[f], 0, 0, 0);
        }
      }
#pragma unroll
      for (int f = 0; f < 7; f++)
        if (f * 16 + l15 >= n) {
          acc[f][0] = -BIG; acc[f][1] = -BIG; acc[f][2] = -BIG; acc[f][3] = -BIG;
        }

#pragma unroll
      for (int e = 0; e < 4; e++) {
        float m = -BIG;
#pragma unroll
        for (int f = 0; f < 7; f++) m = fmaxf(m, acc[f][e]);
        m = fmaxf(m, __shfl_xor(m, 1));
        m = fmaxf(m, __shfl_xor(m, 2));
        m = fmaxf(m, __shfl_xor(m, 4));
        m = fmaxf(m, __shfl_xor(m, 8));
        float p[7], l = 0.f;
#pragma unroll
        for (int f = 0; f < 7; f++) { p[f] = __expf(acc[f][e] - m); l += p[f]; }
        l += __shfl_xor(l, 1);
        l += __shfl_xor(l, 2);
        l += __shfl_xor(l, 4);
        l += __shfl_xor(l, 8);
        const int row = s * 16 + quad * 4 + e;
        float inv = (row < n) ? (1.f / l) : 0.f;
#pragma unroll
        for (int f = 0; f < 7; f++) wl[f] = fmaf(p[f], inv, wl[f]);
      }
    }

#pragma unroll
    for (int f = 0; f < 7; f++) {
      wl[f] += __shfl_xor(wl[f], 16);
      wl[f] += __shfl_xor(wl[f], 32);
    }
    if (lane < 16) {
#pragma unroll
      for (int f = 0; f < 7; f++) w_lds[wv][f * 16 + lane] = wl[f];
    }
    __syncthreads();

    if (tid < NMAX) {
      float t = 0.f;
#pragma unroll
      for (int k = 0; k < 8; k++) t += w_lds[k][tid];
      w_lds[0][tid] = t;
    }
    __syncthreads();
  } else {
    // ---- slow path: private segment, two-pass online softmax ----
    for (int idx = tid; idx < n; idx += 512) seg[i0 + idx] = 0.f;
    __syncthreads();
    for (int lr = wv; lr < n; lr += 8) {
      const uint4* qp4 = (const uint4*)&Qb[(size_t)(i0 + lr) * 64];
      float m_run = -BIG, l_run = 0.f;
      for (int jb = 0; jb < n; jb += 64) {
        int j = jb + lane;
        int jc = min(j, n - 1);
        const uint4* kp4 = (const uint4*)&Kb[(size_t)(i0 + jc) * 64];
        float s = 0.f;
        for (int c = 0; c < 16; c++) {
          uint4 Q1 = qp4[c];
          uint4 K1 = kp4[c];
          s = fmaf(bf_lo(Q1.x), bf_lo(K1.x), s); s = fmaf(bf_hi(Q1.x), bf_hi(K1.x), s);
          s = fmaf(bf_lo(Q1.y), bf_lo(K1.y), s); s = fmaf(bf_hi(Q1.y), bf_hi(K1.y), s);
          s = fmaf(bf_lo(Q1.z), bf_lo(K1.z), s); s = fmaf(bf_hi(Q1.z), bf_hi(K1.z), s);
          s = fmaf(bf_lo(Q1.w), bf_lo(K1.w), s); s = fmaf(bf_hi(Q1.w), bf_hi(K1.w), s);
        }
        if (j >= n) s = -BIG;
        float mc = s;
        for (int off = 32; off; off >>= 1) mc = fmaxf(mc, __shfl_xor(mc, off));
        float m_new = fmaxf(m_run, mc);
        float lc = __expf(s - m_new);
        for (int off = 32; off; off >>= 1) lc += __shfl_xor(lc, off);
        l_run = l_run * __expf(m_run - m_new) + lc;
        m_run = m_new;
      }
      float inv = 1.f / l_run;
      for (int jb = 0; jb < n; jb += 64) {
        int j = jb + lane;
        int jc = min(j, n - 1);
        const uint4* kp4 = (const uint4*)&Kb[(size_t)(i0 + jc) * 64];
        float s = 0.f;
        for (int c = 0; c < 16; c++) {
          uint4 Q1 = qp4[c];
          uint4 K1 = kp4[c];
          s = fmaf(bf_lo(Q1.x), bf_lo(K1.x), s); s = fmaf(bf_hi(Q1.x), bf_hi(K1.x), s);
          s = fmaf(bf_lo(Q1.y), bf_lo(K1.y), s); s = fmaf(bf_hi(Q1.y), bf_hi(K1.y), s);
          s = fmaf(bf_lo(Q1.z), bf_lo(K1.z), s); s = fmaf(bf_hi(Q1.z), bf_hi(K1.z), s);
          s = fmaf(bf_lo(Q1.w), bf_lo(K1.w), s); s = fmaf(bf_hi(Q1.w), bf_hi(K1.w), s);
        }
        if (j < n) atomicAdd(&seg[i0 + j], __expf(s - m_run) * inv);
      }
    }
    __threadfence();
    __syncthreads();
  }

  // ---- u[f] for this block's f-quarter (8-way j-split) ----
  const int fl = tid & 63;
  const int f  = qi * 64 + fl;
  const int jp = tid >> 6;   // 0..7
  float ua = 0.f, ub = 0.f;
  if (fast) {
    int j = jp;
    for (; j + 8 < n; j += 16) {
      ua = fmaf(w_lds[0][j],     X[(size_t)(i0 + j) * N_FEAT + f], ua);
      ub = fmaf(w_lds[0][j + 8], X[(size_t)(i0 + j + 8) * N_FEAT + f], ub);
    }
    for (; j < n; j += 8)
      ua = fmaf(w_lds[0][j], X[(size_t)(i0 + j) * N_FEAT + f], ua);
  } else {
    for (int j = jp; j < n; j += 8) {
      float wj = atomicAdd(&seg[i0 + j], 0.f);   // coherent read
      ua = fmaf(wj, X[(size_t)(i0 + j) * N_FEAT + f], ua);
    }
  }
  red[jp][fl] = ua + ub;
  __syncthreads();
  if (tid < 64) {
    float t = 0.f;
#pragma unroll
    for (int k = 0; k < 8; k++) t += red[k][tid];
    U[g * N_FEAT + qi * 64 + tid] = t;
  }
}

// ---------------------------------------------------------------------------
// Kernel 4: out[g] = U[g] @ Wv.  384 blocks x 512 thr (2 f-halves, 4-way k).
// ---------------------------------------------------------------------------
__global__ __launch_bounds__(512) void vout_o_k(const float* __restrict__ U,
                                                const float* __restrict__ Wv,
                                                float* __restrict__ out) {
  __shared__ float Us[256];
  __shared__ float part[4][128];
  const int g   = blockIdx.x >> 1;
  const int fh  = blockIdx.x & 1;
  const int tid = threadIdx.x;
  const int fl  = tid & 127;
  const int f   = fh * 128 + fl;
  const int kq  = tid >> 7;   // 0..3

  if (tid < 256) Us[tid] = U[g * N_FEAT + tid];
  __syncthreads();

  const int k0 = kq * 64;
  const float* wp = Wv + (size_t)k0 * N_FEAT + f;
  const float* us = &Us[k0];
  float a0 = 0.f, a1 = 0.f, a2 = 0.f, a3 = 0.f;
#pragma unroll 4
  for (int k = 0; k < 64; k += 4) {
    a0 = fmaf(us[k],     wp[(size_t)k * N_FEAT], a0);
    a1 = fmaf(us[k + 1], wp[(size_t)(k + 1) * N_FEAT], a1);
    a2 = fmaf(us[k + 2], wp[(size_t)(k + 2) * N_FEAT], a2);
    a3 = fmaf(us[k + 3], wp[(size_t)(k + 3) * N_FEAT], a3);
  }
  part[kq][fl] = (a0 + a1) + (a2 + a3);
  __syncthreads();
  if (kq == 0)
    out[g * N_FEAT + f] = (part[0][fl] + part[1][fl]) + (part[2][fl] + part[3][fl]);
}

// ---------------------------------------------------------------------------
extern "C" void kernel_launch(void* const* d_in, const int* in_sizes, int n_in,
                              void* d_out, int out_size, void* d_ws, size_t ws_size,
                              hipStream_t stream) {
  const float* X     = (const float*)d_in[0];
  const int*   batch = (const int*)d_in[1];
  const float* Wq    = (const float*)d_in[2];
  const float* Wk    = (const float*)d_in[3];
  const float* Wv    = (const float*)d_in[4];
  float* out = (float*)d_out;

  char* ws = (char*)d_ws;
  int*      starts = (int*)(ws + WS_STARTS);
  float*    U      = (float*)(ws + WS_U);
  float*    wslow  = (float*)(ws + WS_WSLOW);
  unsigned* Qb     = (unsigned*)(ws + WS_QB);
  unsigned* Kb     = (unsigned*)(ws + WS_KB);
  unsigned* Wt     = (unsigned*)(ws + WS_WT);

  wt_prep_k<<<256, 64, 0, stream>>>(Wq, Wk, batch, Wt, starts);
  qk_proj_k<<<N_NODES / 16, 256, 0, stream>>>(X, Wt, Qb, Kb);
  attn_u_k<<<N_GRAPHS * 4, 512, 0, stream>>>(X, starts, Qb, Kb, U, wslow);
  vout_o_k<<<N_GRAPHS * 2, 512, 0, stream>>>(U, Wv, out);
}